// Round 5
// baseline (445.259 us; speedup 1.0000x reference)
//
#include <hip/hip_runtime.h>
#include <math.h>

static constexpr int BATCH = 4;
static constexpr int SEQ   = 2048;
static constexpr int DIM   = 1024;

typedef __attribute__((ext_vector_type(8))) short     bf16x8;  // MFMA A/B frag (4 VGPRs)
typedef __attribute__((ext_vector_type(4))) float     f32x4;   // MFMA C/D frag

// fp32 -> bf16 (RNE) and back, bit-exact helpers for hi/lo splitting
__device__ __forceinline__ unsigned short f2b(float v) {
    unsigned int u = __float_as_uint(v);
    u = u + 0x7fffu + ((u >> 16) & 1u);
    return (unsigned short)(u >> 16);
}
__device__ __forceinline__ float b2f(unsigned short h) {
    return __uint_as_float(((unsigned int)h) << 16);
}

__device__ __forceinline__ void split4(const float4 v, ushort4& h, ushort4& l) {
    h.x = f2b(v.x); l.x = f2b(v.x - b2f(h.x));
    h.y = f2b(v.y); l.y = f2b(v.y - b2f(h.y));
    h.z = f2b(v.z); l.z = f2b(v.z - b2f(h.z));
    h.w = f2b(v.w); l.w = f2b(v.w - b2f(h.w));
}

// ---------------------------------------------------------------------------
// convert_all: one dispatch, block-range partitioned.
//   blocks [0,1024):    X fp32 -> Xhi/Xlo bf16        (2,097,152 float4)
//   blocks [1024,1536): Wq,Wk fp32 -> Whi/Wlo bf16    (524,288 float4, z-major)
//   blocks [1536,1664): Wv -> WvT (transposed hi bf16, 1024 32x32 tiles)
//   blocks [1664,1792): mask int32 -> bitmask (bit n of word (m*2048+n)/32)
// ---------------------------------------------------------------------------
__global__ __launch_bounds__(256) void convert_all_kernel(
    const float* __restrict__ X,  const float* __restrict__ Wq,
    const float* __restrict__ Wk, const float* __restrict__ Wv,
    const int* __restrict__ mask,
    unsigned short* __restrict__ Xhi, unsigned short* __restrict__ Xlo,
    unsigned short* __restrict__ Whi, unsigned short* __restrict__ Wlo,
    unsigned short* __restrict__ WvT, unsigned long long* __restrict__ bm)
{
    __shared__ float t[32][33];
    const int bid = blockIdx.x, tid = threadIdx.x;

    if (bid < 1024) {                       // ---- X hi/lo
        for (int i = bid * 256 + tid; i < (BATCH * SEQ * DIM) / 4; i += 1024 * 256) {
            ushort4 h, l;
            split4(((const float4*)X)[i], h, l);
            ((ushort4*)Xhi)[i] = h;
            ((ushort4*)Xlo)[i] = l;
        }
    } else if (bid < 1536) {                // ---- Wq/Wk hi/lo (no transpose)
        for (int j = (bid - 1024) * 256 + tid; j < 2 * (DIM * DIM / 4); j += 512 * 256) {
            const int z = j / (DIM * DIM / 4);
            const int i = j - z * (DIM * DIM / 4);
            const float4 v = z ? ((const float4*)Wk)[i] : ((const float4*)Wq)[i];
            ushort4 h, l;
            split4(v, h, l);
            ((ushort4*)Whi)[j] = h;
            ((ushort4*)Wlo)[j] = l;
        }
    } else if (bid < 1664) {                // ---- WvT (transpose, hi only)
        const int tx = tid & 31, ty = tid >> 5;       // ty: 0..7
        for (int it = 0; it < 8; ++it) {
            const int tile = (bid - 1536) + 128 * it; // 0..1023
            const int n0 = (tile & 31) * 32, k0 = (tile >> 5) * 32;
#pragma unroll
            for (int i = 0; i < 4; ++i)
                t[ty + i * 8][tx] = Wv[(size_t)(k0 + ty + i * 8) * DIM + (n0 + tx)];
            __syncthreads();
#pragma unroll
            for (int i = 0; i < 4; ++i)
                WvT[(size_t)(n0 + ty + i * 8) * DIM + (k0 + tx)] = f2b(t[tx][ty + i * 8]);
            __syncthreads();
        }
    } else {                                // ---- mask -> bitmask
        const int wave = (bid - 1664) * 4 + (tid >> 6);   // 0..511
        const int lane = tid & 63;
        for (int ch = wave; ch < (SEQ * SEQ) / 64; ch += 512) {
            const int idx = ch * 64 + lane;
            const unsigned long long bal = __ballot(mask[idx] != 0);
            if (lane == 0) bm[ch] = bal;
        }
    }
}

// ---------------------------------------------------------------------------
// Async staging of one 128-row x 32-elem bf16 tile via global_load_lds w=16.
// XOR-swizzled unpadded 64 B rows; wave-uniform LDS dest.
// ---------------------------------------------------------------------------
__device__ __forceinline__ void stage_async(
    const unsigned short* __restrict__ g, int gstride, int row0, int k0,
    unsigned short* lds, int tid)
{
    const int w = tid >> 6, lane = tid & 63;
    const int c = (lane & 3) ^ ((lane >> 4) & 3);   // global chunk this lane fetches
#pragma unroll
    for (int h = 0; h < 2; ++h) {
        const int row = 32 * w + 16 * h + (lane >> 2);
        const unsigned short* src = g + (size_t)(row0 + row) * gstride + k0 + 8 * c;
        unsigned short* dst = lds + (32 * w + 16 * h) * 32;   // wave-uniform
        __builtin_amdgcn_global_load_lds(
            (const __attribute__((address_space(1))) void*)src,
            (__attribute__((address_space(3))) void*)dst, 16, 0, 0);
    }
}

__device__ __forceinline__ bf16x8 fragr(const unsigned short* lds, int row, int qsw)
{
    return *(const bf16x8*)(lds + row * 32 + qsw * 8);
}

// ---------------------------------------------------------------------------
// m_gemm: Mt = Wk . Wq^T, 3-term split bf16, 128x128 tile,
// K-split over z (8 chunks of 128). fp32 partials.
// ---------------------------------------------------------------------------
__global__ __launch_bounds__(256) void m_gemm_kernel(
    const unsigned short* __restrict__ Whi, const unsigned short* __restrict__ Wlo,
    float* __restrict__ Mtp)
{
    __shared__ unsigned short Ah[128 * 32], Al[128 * 32];
    __shared__ unsigned short Bh[128 * 32], Bl[128 * 32];

    const int tid = threadIdx.x;
    const int w = tid >> 6, lane = tid & 63;
    const int wm = (w >> 1) * 64, wn = (w & 1) * 64;
    const int m0 = blockIdx.y * 128, n0 = blockIdx.x * 128;
    const int z = blockIdx.z;                        // K chunk (8 x 128)

    const unsigned short* __restrict__ Ahg = Whi + (size_t)DIM * DIM;  // Wk hi
    const unsigned short* __restrict__ Alg = Wlo + (size_t)DIM * DIM;  // Wk lo
    const unsigned short* __restrict__ Bhg = Whi;                      // Wq hi
    const unsigned short* __restrict__ Blg = Wlo;                      // Wq lo
    float* __restrict__ Cp = Mtp + (size_t)z * DIM * DIM;

    f32x4 acc[4][4];
#pragma unroll
    for (int i = 0; i < 4; ++i)
#pragma unroll
        for (int j = 0; j < 4; ++j) acc[i][j] = (f32x4){0.f, 0.f, 0.f, 0.f};

    const int fr = lane & 15, quad = lane >> 4;
    const int qsw = quad ^ ((fr >> 2) & 3);

    for (int k0 = z * 128; k0 < z * 128 + 128; k0 += 32) {
        stage_async(Ahg, DIM, m0, k0, Ah, tid);
        stage_async(Alg, DIM, m0, k0, Al, tid);
        stage_async(Bhg, DIM, n0, k0, Bh, tid);
        stage_async(Blg, DIM, n0, k0, Bl, tid);
        __syncthreads();

        bf16x8 ah[4], al[4];
#pragma unroll
        for (int mt = 0; mt < 4; ++mt) {
            ah[mt] = fragr(Ah, wm + mt * 16 + fr, qsw);
            al[mt] = fragr(Al, wm + mt * 16 + fr, qsw);
        }
#pragma unroll
        for (int nt = 0; nt < 4; ++nt) {
            const bf16x8 bh = fragr(Bh, wn + nt * 16 + fr, qsw);
            const bf16x8 bl = fragr(Bl, wn + nt * 16 + fr, qsw);
#pragma unroll
            for (int mt = 0; mt < 4; ++mt) {
                acc[mt][nt] = __builtin_amdgcn_mfma_f32_16x16x32_bf16(ah[mt], bh, acc[mt][nt], 0, 0, 0);
                acc[mt][nt] = __builtin_amdgcn_mfma_f32_16x16x32_bf16(ah[mt], bl, acc[mt][nt], 0, 0, 0);
                acc[mt][nt] = __builtin_amdgcn_mfma_f32_16x16x32_bf16(al[mt], bh, acc[mt][nt], 0, 0, 0);
            }
        }
        __syncthreads();
    }

    const int col = lane & 15, rq = lane >> 4;
#pragma unroll
    for (int mt = 0; mt < 4; ++mt)
#pragma unroll
        for (int nt = 0; nt < 4; ++nt)
#pragma unroll
            for (int e = 0; e < 4; ++e) {
                const int m = m0 + wm + mt * 16 + rq * 4 + e;
                const int n = n0 + wn + nt * 16 + col;
                Cp[(size_t)m * DIM + n] = acc[mt][nt][e];
            }
}

// ---------------------------------------------------------------------------
// m_reduce: sum 8 K-split partials, split to hi/lo bf16.
// ---------------------------------------------------------------------------
__global__ __launch_bounds__(256) void m_reduce_kernel(
    const float* __restrict__ Mtp, unsigned short* __restrict__ Mthi,
    unsigned short* __restrict__ Mtlo)
{
    const int i = blockIdx.x * 256 + threadIdx.x;   // float4 index
    const size_t q = (size_t)DIM * DIM / 4;
    float4 v = ((const float4*)Mtp)[i];
#pragma unroll
    for (int p = 1; p < 8; ++p) {
        const float4 a = ((const float4*)Mtp)[i + p * q];
        v.x += a.x; v.y += a.y; v.z += a.z; v.w += a.w;
    }
    ushort4 h, l;
    split4(v, h, l);
    ((ushort4*)Mthi)[i] = h;
    ((ushort4*)Mtlo)[i] = l;
}

// ---------------------------------------------------------------------------
// yv_gemm: z=0 -> Y = X @ Mt^T (3-term, hi/lo out, [8192][1024])
//          z=1 -> V = X @ WvT^T (1-term), written TRANSPOSED as Vt[b][d][s]
// ---------------------------------------------------------------------------
__global__ __launch_bounds__(256) void yv_gemm_kernel(
    const unsigned short* __restrict__ Xhi, const unsigned short* __restrict__ Xlo,
    const unsigned short* __restrict__ Mthi, const unsigned short* __restrict__ Mtlo,
    const unsigned short* __restrict__ WvT,
    unsigned short* __restrict__ Yhi, unsigned short* __restrict__ Ylo,
    unsigned short* __restrict__ Vt)
{
    __shared__ unsigned short Ah[128 * 32], Al[128 * 32];
    __shared__ unsigned short Bh[128 * 32], Bl[128 * 32];

    const int tid = threadIdx.x;
    const int w = tid >> 6, lane = tid & 63;
    const int wm = (w >> 1) * 64, wn = (w & 1) * 64;
    const int m0 = blockIdx.y * 128, n0 = blockIdx.x * 128;
    const int z = blockIdx.z;
    const bool full = (z == 0);

    const unsigned short* __restrict__ Bhg = full ? Mthi : WvT;
    const unsigned short* __restrict__ Blg = Mtlo;

    f32x4 acc[4][4];
#pragma unroll
    for (int i = 0; i < 4; ++i)
#pragma unroll
        for (int j = 0; j < 4; ++j) acc[i][j] = (f32x4){0.f, 0.f, 0.f, 0.f};

    const int fr = lane & 15, quad = lane >> 4;
    const int qsw = quad ^ ((fr >> 2) & 3);

    for (int k0 = 0; k0 < DIM; k0 += 32) {
        stage_async(Xhi, DIM, m0, k0, Ah, tid);
        stage_async(Bhg, DIM, n0, k0, Bh, tid);
        if (full) {
            stage_async(Xlo, DIM, m0, k0, Al, tid);
            stage_async(Blg, DIM, n0, k0, Bl, tid);
        }
        __syncthreads();

        bf16x8 ah[4], al[4];
#pragma unroll
        for (int mt = 0; mt < 4; ++mt)
            ah[mt] = fragr(Ah, wm + mt * 16 + fr, qsw);
        if (full) {
#pragma unroll
            for (int mt = 0; mt < 4; ++mt)
                al[mt] = fragr(Al, wm + mt * 16 + fr, qsw);
        }
#pragma unroll
        for (int nt = 0; nt < 4; ++nt) {
            const bf16x8 bh = fragr(Bh, wn + nt * 16 + fr, qsw);
#pragma unroll
            for (int mt = 0; mt < 4; ++mt)
                acc[mt][nt] = __builtin_amdgcn_mfma_f32_16x16x32_bf16(ah[mt], bh, acc[mt][nt], 0, 0, 0);
            if (full) {
                const bf16x8 bl = fragr(Bl, wn + nt * 16 + fr, qsw);
#pragma unroll
                for (int mt = 0; mt < 4; ++mt) {
                    acc[mt][nt] = __builtin_amdgcn_mfma_f32_16x16x32_bf16(ah[mt], bl, acc[mt][nt], 0, 0, 0);
                    acc[mt][nt] = __builtin_amdgcn_mfma_f32_16x16x32_bf16(al[mt], bh, acc[mt][nt], 0, 0, 0);
                }
            }
        }
        __syncthreads();
    }

    const int col = lane & 15, rq = lane >> 4;
    if (full) {
#pragma unroll
        for (int mt = 0; mt < 4; ++mt)
#pragma unroll
            for (int nt = 0; nt < 4; ++nt)
#pragma unroll
                for (int e = 0; e < 4; ++e) {
                    const int m = m0 + wm + mt * 16 + rq * 4 + e;
                    const int n = n0 + wn + nt * 16 + col;
                    const float v = acc[mt][nt][e];
                    const unsigned short h = f2b(v);
                    Yhi[(size_t)m * DIM + n] = h;
                    Ylo[(size_t)m * DIM + n] = f2b(v - b2f(h));
                }
    } else {
        // V: write transposed, Vt[b][n][s], 4 consecutive s per ushort4
#pragma unroll
        for (int mt = 0; mt < 4; ++mt)
#pragma unroll
            for (int nt = 0; nt < 4; ++nt) {
                const int m = m0 + wm + mt * 16 + rq * 4;      // 4-aligned
                const int bb = m >> 11, s = m & (SEQ - 1);
                const int n = n0 + wn + nt * 16 + col;
                ushort4 pk;
                pk.x = f2b(acc[mt][nt][0]);
                pk.y = f2b(acc[mt][nt][1]);
                pk.z = f2b(acc[mt][nt][2]);
                pk.w = f2b(acc[mt][nt][3]);
                *(ushort4*)(Vt + (size_t)bb * DIM * SEQ + (size_t)n * SEQ + s) = pk;
            }
    }
}

// ---------------------------------------------------------------------------
// s_gemm: S[b] = (Y[b] . X[b]^T) * 1/32, masked to -inf via 512 KB bitmask.
// 3-term split bf16; A = Y hi/lo, B = X hi/lo (per batch). fp32 output.
// ---------------------------------------------------------------------------
__global__ __launch_bounds__(256) void s_gemm_kernel(
    const unsigned short* __restrict__ Yhi, const unsigned short* __restrict__ Ylo,
    const unsigned short* __restrict__ Xhi, const unsigned short* __restrict__ Xlo,
    const unsigned int* __restrict__ bm, float* __restrict__ Sc)
{
    __shared__ unsigned short Ah[128 * 32], Al[128 * 32];
    __shared__ unsigned short Bh[128 * 32], Bl[128 * 32];

    const int tid = threadIdx.x;
    const int w = tid >> 6, lane = tid & 63;
    const int wm = (w >> 1) * 64, wn = (w & 1) * 64;
    const int m0 = blockIdx.y * 128, n0 = blockIdx.x * 128;
    const int b = blockIdx.z;

    const unsigned short* __restrict__ Ahg = Yhi + (size_t)b * SEQ * DIM;
    const unsigned short* __restrict__ Alg = Ylo + (size_t)b * SEQ * DIM;
    const unsigned short* __restrict__ Bhg = Xhi + (size_t)b * SEQ * DIM;
    const unsigned short* __restrict__ Blg = Xlo + (size_t)b * SEQ * DIM;
    float* __restrict__ Sb = Sc + (size_t)b * SEQ * SEQ;

    f32x4 acc[4][4];
#pragma unroll
    for (int i = 0; i < 4; ++i)
#pragma unroll
        for (int j = 0; j < 4; ++j) acc[i][j] = (f32x4){0.f, 0.f, 0.f, 0.f};

    const int fr = lane & 15, quad = lane >> 4;
    const int qsw = quad ^ ((fr >> 2) & 3);

    for (int k0 = 0; k0 < DIM; k0 += 32) {
        stage_async(Ahg, DIM, m0, k0, Ah, tid);
        stage_async(Alg, DIM, m0, k0, Al, tid);
        stage_async(Bhg, DIM, n0, k0, Bh, tid);
        stage_async(Blg, DIM, n0, k0, Bl, tid);
        __syncthreads();

        bf16x8 ah[4], al[4];
#pragma unroll
        for (int mt = 0; mt < 4; ++mt) {
            ah[mt] = fragr(Ah, wm + mt * 16 + fr, qsw);
            al[mt] = fragr(Al, wm + mt * 16 + fr, qsw);
        }
#pragma unroll
        for (int nt = 0; nt < 4; ++nt) {
            const bf16x8 bh = fragr(Bh, wn + nt * 16 + fr, qsw);
            const bf16x8 bl = fragr(Bl, wn + nt * 16 + fr, qsw);
#pragma unroll
            for (int mt = 0; mt < 4; ++mt) {
                acc[mt][nt] = __builtin_amdgcn_mfma_f32_16x16x32_bf16(ah[mt], bh, acc[mt][nt], 0, 0, 0);
                acc[mt][nt] = __builtin_amdgcn_mfma_f32_16x16x32_bf16(ah[mt], bl, acc[mt][nt], 0, 0, 0);
                acc[mt][nt] = __builtin_amdgcn_mfma_f32_16x16x32_bf16(al[mt], bh, acc[mt][nt], 0, 0, 0);
            }
        }
        __syncthreads();
    }

    const int col = lane & 15, rq = lane >> 4;
#pragma unroll
    for (int mt = 0; mt < 4; ++mt)
#pragma unroll
        for (int nt = 0; nt < 4; ++nt)
#pragma unroll
            for (int e = 0; e < 4; ++e) {
                const int m = m0 + wm + mt * 16 + rq * 4 + e;
                const int n = n0 + wn + nt * 16 + col;
                const float v = acc[mt][nt][e] * 0.03125f;
                const unsigned int w32 = bm[((size_t)m * SEQ + n) >> 5];
                Sb[(size_t)m * SEQ + n] = ((w32 >> (n & 31)) & 1u) ? -INFINITY : v;
            }
}

// ---------------------------------------------------------------------------
// Row softmax on pre-masked, pre-scaled fp32 S; writes bf16 P in place
// (row r -> first 2048 ushorts of the row's 16 KB).
// ---------------------------------------------------------------------------
__global__ __launch_bounds__(256) void softmax_kernel(float* __restrict__ Sc)
{
    const int r = blockIdx.x;          // b*2048 + m
    float* __restrict__ row = Sc + (size_t)r * SEQ;

    const int tid  = threadIdx.x;
    const int lane = tid & 63;
    const int wid  = tid >> 6;

    float x[8];
    float mx = -INFINITY;
#pragma unroll
    for (int j = 0; j < 8; ++j) {
        x[j] = row[tid + j * 256];
        mx = fmaxf(mx, x[j]);
    }
    __shared__ float redm[4];
#pragma unroll
    for (int off = 32; off > 0; off >>= 1)
        mx = fmaxf(mx, __shfl_down(mx, off, 64));
    if (lane == 0) redm[wid] = mx;
    __syncthreads();
    mx = fmaxf(fmaxf(redm[0], redm[1]), fmaxf(redm[2], redm[3]));

    float sum = 0.f;
#pragma unroll
    for (int j = 0; j < 8; ++j) {
        const float e = __expf(x[j] - mx);
        x[j] = e;
        sum += e;
    }
    __shared__ float reds[4];
#pragma unroll
    for (int off = 32; off > 0; off >>= 1)
        sum += __shfl_down(sum, off, 64);
    if (lane == 0) reds[wid] = sum;
    __syncthreads();
    sum = (reds[0] + reds[1]) + (reds[2] + reds[3]);

    const float inv = 1.0f / sum;
    unsigned short* __restrict__ prow = (unsigned short*)row;
#pragma unroll
    for (int j = 0; j < 8; ++j)
        prow[tid + j * 256] = f2b(x[j] * inv);
}

// ---------------------------------------------------------------------------
// O[b] = P[b] @ V[b]: single bf16 MFMA, BK=64 (two staged sub-tiles/barrier).
// A = P rows (stride 4096 ushorts), B = Vt rows (n-major, k contiguous).
// ---------------------------------------------------------------------------
__global__ __launch_bounds__(256) void pv_mfma_kernel(
    const unsigned short* __restrict__ P, const unsigned short* __restrict__ Vt,
    float* __restrict__ O)
{
    __shared__ unsigned short As[2][128 * 32], Bs[2][128 * 32];

    const int tid = threadIdx.x;
    const int w = tid >> 6, lane = tid & 63;
    const int wm = (w >> 1) * 64, wn = (w & 1) * 64;
    const int m0 = blockIdx.y * 128, n0 = blockIdx.x * 128;
    const int b = blockIdx.z;

    const unsigned short* __restrict__ Ag = P + (size_t)b * SEQ * (2 * SEQ);
    const unsigned short* __restrict__ Bg = Vt + (size_t)b * DIM * SEQ;
    float* __restrict__ Ob = O + (size_t)b * SEQ * DIM;

    f32x4 acc[4][4];
#pragma unroll
    for (int i = 0; i < 4; ++i)
#pragma unroll
        for (int j = 0; j < 4; ++j) acc[i][j] = (f32x4){0.f, 0.f, 0.f, 0.f};

    const int fr = lane & 15, quad = lane >> 4;
    const int qsw = quad ^ ((fr >> 2) & 3);

    for (int k0 = 0; k0 < SEQ; k0 += 64) {
        stage_async(Ag, 2 * SEQ, m0, k0,      As[0], tid);
        stage_async(Ag, 2 * SEQ, m0, k0 + 32, As[1], tid);
        stage_async(Bg, SEQ,     n0, k0,      Bs[0], tid);
        stage_async(Bg, SEQ,     n0, k0 + 32, Bs[1], tid);
        __syncthreads();

#pragma unroll
        for (int s = 0; s < 2; ++s) {
            bf16x8 af[4];
#pragma unroll
            for (int mt = 0; mt < 4; ++mt)
                af[mt] = fragr(As[s], wm + mt * 16 + fr, qsw);
#pragma unroll
            for (int nt = 0; nt < 4; ++nt) {
                const bf16x8 bfg = fragr(Bs[s], wn + nt * 16 + fr, qsw);
#pragma unroll
                for (int mt = 0; mt < 4; ++mt)
                    acc[mt][nt] = __builtin_amdgcn_mfma_f32_16x16x32_bf16(af[mt], bfg, acc[mt][nt], 0, 0, 0);
            }
        }
        __syncthreads();
    }

    const int col = lane & 15, rq = lane >> 4;
#pragma unroll
    for (int mt = 0; mt < 4; ++mt)
#pragma unroll
        for (int nt = 0; nt < 4; ++nt)
#pragma unroll
            for (int e = 0; e < 4; ++e) {
                const int m = m0 + wm + mt * 16 + rq * 4 + e;
                const int n = n0 + wn + nt * 16 + col;
                Ob[(size_t)m * DIM + n] = acc[mt][nt][e];
            }
}

// ---------------------------------------------------------------------------
// Workspace layout (bytes), total used = 155 713 536 (<= 167 772 160):
//   Xhi/Xlo/Yhi/Ylo/Vt : 5 x 16 777 216   (bf16 [8192][1024]-sized each)
//   Mthi/Mtlo          : 2 x  2 097 152   (bf16 [1024][1024])
//   Sc                 : 67 108 864       (fp32 [4][2048][2048])
//   bitmask            :    524 288       (after Sc; persists through s_gemm)
// Transients aliased INSIDE Sc (consumed before s_gemm writes Sc):
//   Whi/Wlo (2x4.2 MB) + WvT (2.1 MB) + Mtp (8x4.2 MB fp32) = 44.0 MB
// P (bf16) written in place into Sc rows (row r at ushort offset r*4096).
// ---------------------------------------------------------------------------
extern "C" void kernel_launch(void* const* d_in, const int* in_sizes, int n_in,
                              void* d_out, int out_size, void* d_ws, size_t ws_size,
                              hipStream_t stream)
{
    const float* x    = (const float*)d_in[0];
    const int*   mask = (const int*)d_in[1];
    const float* wq   = (const float*)d_in[2];
    const float* wk   = (const float*)d_in[3];
    const float* wv   = (const float*)d_in[4];
    float* out = (float*)d_out;

    const size_t NQ = (size_t)BATCH * SEQ * DIM;     // 8 388 608
    const size_t NM = (size_t)DIM * DIM;             // 1 048 576
    unsigned short* Xhi  = (unsigned short*)d_ws;
    unsigned short* Xlo  = Xhi + NQ;
    unsigned short* Yhi  = Xlo + NQ;
    unsigned short* Ylo  = Yhi + NQ;
    unsigned short* Vt   = Ylo + NQ;
    unsigned short* Mthi = Vt + NQ;
    unsigned short* Mtlo = Mthi + NM;
    float* Sc = (float*)(Mtlo + NM);
    unsigned long long* bm = (unsigned long long*)(Sc + (size_t)BATCH * SEQ * SEQ);

    unsigned short* Whi = (unsigned short*)Sc;       // transient aliases in Sc
    unsigned short* Wlo = Whi + 2 * NM;
    unsigned short* WvT = Wlo + 2 * NM;
    float* Mtp = (float*)(WvT + NM);                 // 8 x NM fp32

    // 1. One dispatch: X hi/lo, Wq/Wk hi/lo, WvT, mask -> bitmask
    convert_all_kernel<<<dim3(1792), 256, 0, stream>>>(
        x, wq, wk, wv, mask, Xhi, Xlo, Whi, Wlo, WvT, bm);
    // 2. Mt = Wk.Wq^T (K-split x8, fp32 partials), then reduce + hi/lo split
    m_gemm_kernel<<<dim3(8, 8, 8), 256, 0, stream>>>(Whi, Wlo, Mtp);
    m_reduce_kernel<<<dim3(NM / 4 / 256), 256, 0, stream>>>(Mtp, Mthi, Mtlo);
    // 3. z=0: Y = X.Mt^T (hi/lo out); z=1: V = X.WvT^T written as Vt[b][d][s]
    yv_gemm_kernel<<<dim3(DIM / 128, (BATCH * SEQ) / 128, 2), 256, 0, stream>>>(
        Xhi, Xlo, Mthi, Mtlo, WvT, Yhi, Ylo, Vt);
    // 4. S = masked, scaled Y.X^T per batch (fp32 scores, bitmask)
    s_gemm_kernel<<<dim3(SEQ / 128, SEQ / 128, BATCH), 256, 0, stream>>>(
        Yhi, Ylo, Xhi, Xlo, (const unsigned int*)bm, Sc);
    // 5. softmax; writes bf16 P in place
    softmax_kernel<<<dim3(BATCH * SEQ), 256, 0, stream>>>(Sc);
    // 6. O = P @ V
    pv_mfma_kernel<<<dim3(DIM / 128, SEQ / 128, BATCH), 256, 0, stream>>>(
        (const unsigned short*)Sc, Vt, out);
}

// Round 6
// 395.523 us; speedup vs baseline: 1.1257x; 1.1257x over previous
//
#include <hip/hip_runtime.h>
#include <math.h>

static constexpr int BATCH = 4;
static constexpr int SEQ   = 2048;
static constexpr int DIM   = 1024;

typedef __attribute__((ext_vector_type(8))) short     bf16x8;  // MFMA A/B frag (4 VGPRs)
typedef __attribute__((ext_vector_type(4))) float     f32x4;   // MFMA C/D frag

// fp32 -> bf16 (RNE) and back, bit-exact helpers for hi/lo splitting
__device__ __forceinline__ unsigned short f2b(float v) {
    unsigned int u = __float_as_uint(v);
    u = u + 0x7fffu + ((u >> 16) & 1u);
    return (unsigned short)(u >> 16);
}
__device__ __forceinline__ float b2f(unsigned short h) {
    return __uint_as_float(((unsigned int)h) << 16);
}

__device__ __forceinline__ void split4(const float4 v, ushort4& h, ushort4& l) {
    h.x = f2b(v.x); l.x = f2b(v.x - b2f(h.x));
    h.y = f2b(v.y); l.y = f2b(v.y - b2f(h.y));
    h.z = f2b(v.z); l.z = f2b(v.z - b2f(h.z));
    h.w = f2b(v.w); l.w = f2b(v.w - b2f(h.w));
}

// ---------------------------------------------------------------------------
// convert_all: one dispatch, block-range partitioned. Balanced so no section
// is a latency straggler (round-5 lesson: 512-wave mask section serialized
// 128 ballot iterations -> ~48 us tail; now 2048 waves x 32 pipelined iters).
//   blocks [0,1024):    X fp32 -> Xhi/Xlo bf16        (2,097,152 float4)
//   blocks [1024,1536): Wq,Wk fp32 -> Whi/Wlo bf16    (524,288 float4, z-major)
//   blocks [1536,1664): Wv -> WvT (transposed hi bf16, 1024 32x32 tiles)
//   blocks [1664,2176): mask int32 -> bitmask (bit n of word (m*2048+n)/64)
// ---------------------------------------------------------------------------
__global__ __launch_bounds__(256) void convert_all_kernel(
    const float* __restrict__ X,  const float* __restrict__ Wq,
    const float* __restrict__ Wk, const float* __restrict__ Wv,
    const int* __restrict__ mask,
    unsigned short* __restrict__ Xhi, unsigned short* __restrict__ Xlo,
    unsigned short* __restrict__ Whi, unsigned short* __restrict__ Wlo,
    unsigned short* __restrict__ WvT, unsigned long long* __restrict__ bm)
{
    __shared__ float t[32][33];
    const int bid = blockIdx.x, tid = threadIdx.x;

    if (bid < 1024) {                       // ---- X hi/lo
        for (int i = bid * 256 + tid; i < (BATCH * SEQ * DIM) / 4; i += 1024 * 256) {
            ushort4 h, l;
            split4(((const float4*)X)[i], h, l);
            ((ushort4*)Xhi)[i] = h;
            ((ushort4*)Xlo)[i] = l;
        }
    } else if (bid < 1536) {                // ---- Wq/Wk hi/lo (no transpose)
        for (int j = (bid - 1024) * 256 + tid; j < 2 * (DIM * DIM / 4); j += 512 * 256) {
            const int z = j / (DIM * DIM / 4);
            const int i = j - z * (DIM * DIM / 4);
            const float4 v = z ? ((const float4*)Wk)[i] : ((const float4*)Wq)[i];
            ushort4 h, l;
            split4(v, h, l);
            ((ushort4*)Whi)[j] = h;
            ((ushort4*)Wlo)[j] = l;
        }
    } else if (bid < 1664) {                // ---- WvT (transpose, hi only)
        const int tx = tid & 31, ty = tid >> 5;       // ty: 0..7
        for (int it = 0; it < 8; ++it) {
            const int tile = (bid - 1536) + 128 * it; // 0..1023
            const int n0 = (tile & 31) * 32, k0 = (tile >> 5) * 32;
#pragma unroll
            for (int i = 0; i < 4; ++i)
                t[ty + i * 8][tx] = Wv[(size_t)(k0 + ty + i * 8) * DIM + (n0 + tx)];
            __syncthreads();
#pragma unroll
            for (int i = 0; i < 4; ++i)
                WvT[(size_t)(n0 + ty + i * 8) * DIM + (k0 + tx)] = f2b(t[tx][ty + i * 8]);
            __syncthreads();
        }
    } else {                                // ---- mask -> bitmask, 2048 waves
        const int wave = (bid - 1664) * 4 + (tid >> 6);   // 0..2047
        const int lane = tid & 63;
#pragma unroll 4
        for (int it = 0; it < 32; ++it) {                 // 65536 / 2048 chunks
            const int ch = wave + it * 2048;
            const unsigned long long bal = __ballot(mask[ch * 64 + lane] != 0);
            if (lane == 0) bm[ch] = bal;
        }
    }
}

// ---------------------------------------------------------------------------
// Async staging of one 128-row x 32-elem bf16 tile via global_load_lds w=16.
// XOR-swizzled unpadded 64 B rows; wave-uniform LDS dest.
// ---------------------------------------------------------------------------
__device__ __forceinline__ void stage_async(
    const unsigned short* __restrict__ g, int gstride, int row0, int k0,
    unsigned short* lds, int tid)
{
    const int w = tid >> 6, lane = tid & 63;
    const int c = (lane & 3) ^ ((lane >> 4) & 3);   // global chunk this lane fetches
#pragma unroll
    for (int h = 0; h < 2; ++h) {
        const int row = 32 * w + 16 * h + (lane >> 2);
        const unsigned short* src = g + (size_t)(row0 + row) * gstride + k0 + 8 * c;
        unsigned short* dst = lds + (32 * w + 16 * h) * 32;   // wave-uniform
        __builtin_amdgcn_global_load_lds(
            (const __attribute__((address_space(1))) void*)src,
            (__attribute__((address_space(3))) void*)dst, 16, 0, 0);
    }
}

__device__ __forceinline__ bf16x8 fragr(const unsigned short* lds, int row, int qsw)
{
    return *(const bf16x8*)(lds + row * 32 + qsw * 8);
}

// ---------------------------------------------------------------------------
// m_gemm: Mt = Wk . Wq^T, 3-term split bf16, 128x128 tile,
// K-split over z (8 chunks of 128). fp32 partials.
// ---------------------------------------------------------------------------
__global__ __launch_bounds__(256) void m_gemm_kernel(
    const unsigned short* __restrict__ Whi, const unsigned short* __restrict__ Wlo,
    float* __restrict__ Mtp)
{
    __shared__ unsigned short Ah[128 * 32], Al[128 * 32];
    __shared__ unsigned short Bh[128 * 32], Bl[128 * 32];

    const int tid = threadIdx.x;
    const int w = tid >> 6, lane = tid & 63;
    const int wm = (w >> 1) * 64, wn = (w & 1) * 64;
    const int m0 = blockIdx.y * 128, n0 = blockIdx.x * 128;
    const int z = blockIdx.z;                        // K chunk (8 x 128)

    const unsigned short* __restrict__ Ahg = Whi + (size_t)DIM * DIM;  // Wk hi
    const unsigned short* __restrict__ Alg = Wlo + (size_t)DIM * DIM;  // Wk lo
    const unsigned short* __restrict__ Bhg = Whi;                      // Wq hi
    const unsigned short* __restrict__ Blg = Wlo;                      // Wq lo
    float* __restrict__ Cp = Mtp + (size_t)z * DIM * DIM;

    f32x4 acc[4][4];
#pragma unroll
    for (int i = 0; i < 4; ++i)
#pragma unroll
        for (int j = 0; j < 4; ++j) acc[i][j] = (f32x4){0.f, 0.f, 0.f, 0.f};

    const int fr = lane & 15, quad = lane >> 4;
    const int qsw = quad ^ ((fr >> 2) & 3);

    for (int k0 = z * 128; k0 < z * 128 + 128; k0 += 32) {
        stage_async(Ahg, DIM, m0, k0, Ah, tid);
        stage_async(Alg, DIM, m0, k0, Al, tid);
        stage_async(Bhg, DIM, n0, k0, Bh, tid);
        stage_async(Blg, DIM, n0, k0, Bl, tid);
        __syncthreads();

        bf16x8 ah[4], al[4];
#pragma unroll
        for (int mt = 0; mt < 4; ++mt) {
            ah[mt] = fragr(Ah, wm + mt * 16 + fr, qsw);
            al[mt] = fragr(Al, wm + mt * 16 + fr, qsw);
        }
#pragma unroll
        for (int nt = 0; nt < 4; ++nt) {
            const bf16x8 bh = fragr(Bh, wn + nt * 16 + fr, qsw);
            const bf16x8 bl = fragr(Bl, wn + nt * 16 + fr, qsw);
#pragma unroll
            for (int mt = 0; mt < 4; ++mt) {
                acc[mt][nt] = __builtin_amdgcn_mfma_f32_16x16x32_bf16(ah[mt], bh, acc[mt][nt], 0, 0, 0);
                acc[mt][nt] = __builtin_amdgcn_mfma_f32_16x16x32_bf16(ah[mt], bl, acc[mt][nt], 0, 0, 0);
                acc[mt][nt] = __builtin_amdgcn_mfma_f32_16x16x32_bf16(al[mt], bh, acc[mt][nt], 0, 0, 0);
            }
        }
        __syncthreads();
    }

    const int col = lane & 15, rq = lane >> 4;
#pragma unroll
    for (int mt = 0; mt < 4; ++mt)
#pragma unroll
        for (int nt = 0; nt < 4; ++nt)
#pragma unroll
            for (int e = 0; e < 4; ++e) {
                const int m = m0 + wm + mt * 16 + rq * 4 + e;
                const int n = n0 + wn + nt * 16 + col;
                Cp[(size_t)m * DIM + n] = acc[mt][nt][e];
            }
}

// ---------------------------------------------------------------------------
// m_reduce: sum 8 K-split partials, split to hi/lo bf16.
// ---------------------------------------------------------------------------
__global__ __launch_bounds__(256) void m_reduce_kernel(
    const float* __restrict__ Mtp, unsigned short* __restrict__ Mthi,
    unsigned short* __restrict__ Mtlo)
{
    const int i = blockIdx.x * 256 + threadIdx.x;   // float4 index
    const size_t q = (size_t)DIM * DIM / 4;
    float4 v = ((const float4*)Mtp)[i];
#pragma unroll
    for (int p = 1; p < 8; ++p) {
        const float4 a = ((const float4*)Mtp)[i + p * q];
        v.x += a.x; v.y += a.y; v.z += a.z; v.w += a.w;
    }
    ushort4 h, l;
    split4(v, h, l);
    ((ushort4*)Mthi)[i] = h;
    ((ushort4*)Mtlo)[i] = l;
}

// ---------------------------------------------------------------------------
// yv_gemm: z=0 -> Y = X @ Mt^T (3-term, hi/lo out, [8192][1024])
//          z=1 -> V = X @ WvT^T (1-term), written TRANSPOSED as Vt[b][d][s]
// ---------------------------------------------------------------------------
__global__ __launch_bounds__(256) void yv_gemm_kernel(
    const unsigned short* __restrict__ Xhi, const unsigned short* __restrict__ Xlo,
    const unsigned short* __restrict__ Mthi, const unsigned short* __restrict__ Mtlo,
    const unsigned short* __restrict__ WvT,
    unsigned short* __restrict__ Yhi, unsigned short* __restrict__ Ylo,
    unsigned short* __restrict__ Vt)
{
    __shared__ unsigned short Ah[128 * 32], Al[128 * 32];
    __shared__ unsigned short Bh[128 * 32], Bl[128 * 32];

    const int tid = threadIdx.x;
    const int w = tid >> 6, lane = tid & 63;
    const int wm = (w >> 1) * 64, wn = (w & 1) * 64;
    const int m0 = blockIdx.y * 128, n0 = blockIdx.x * 128;
    const int z = blockIdx.z;
    const bool full = (z == 0);

    const unsigned short* __restrict__ Bhg = full ? Mthi : WvT;
    const unsigned short* __restrict__ Blg = Mtlo;

    f32x4 acc[4][4];
#pragma unroll
    for (int i = 0; i < 4; ++i)
#pragma unroll
        for (int j = 0; j < 4; ++j) acc[i][j] = (f32x4){0.f, 0.f, 0.f, 0.f};

    const int fr = lane & 15, quad = lane >> 4;
    const int qsw = quad ^ ((fr >> 2) & 3);

    for (int k0 = 0; k0 < DIM; k0 += 32) {
        stage_async(Xhi, DIM, m0, k0, Ah, tid);
        stage_async(Bhg, DIM, n0, k0, Bh, tid);
        if (full) {
            stage_async(Xlo, DIM, m0, k0, Al, tid);
            stage_async(Blg, DIM, n0, k0, Bl, tid);
        }
        __syncthreads();

        bf16x8 ah[4], al[4];
#pragma unroll
        for (int mt = 0; mt < 4; ++mt)
            ah[mt] = fragr(Ah, wm + mt * 16 + fr, qsw);
        if (full) {
#pragma unroll
            for (int mt = 0; mt < 4; ++mt)
                al[mt] = fragr(Al, wm + mt * 16 + fr, qsw);
        }
#pragma unroll
        for (int nt = 0; nt < 4; ++nt) {
            const bf16x8 bh = fragr(Bh, wn + nt * 16 + fr, qsw);
#pragma unroll
            for (int mt = 0; mt < 4; ++mt)
                acc[mt][nt] = __builtin_amdgcn_mfma_f32_16x16x32_bf16(ah[mt], bh, acc[mt][nt], 0, 0, 0);
            if (full) {
                const bf16x8 bl = fragr(Bl, wn + nt * 16 + fr, qsw);
#pragma unroll
                for (int mt = 0; mt < 4; ++mt) {
                    acc[mt][nt] = __builtin_amdgcn_mfma_f32_16x16x32_bf16(ah[mt], bl, acc[mt][nt], 0, 0, 0);
                    acc[mt][nt] = __builtin_amdgcn_mfma_f32_16x16x32_bf16(al[mt], bh, acc[mt][nt], 0, 0, 0);
                }
            }
        }
        __syncthreads();
    }

    const int col = lane & 15, rq = lane >> 4;
    if (full) {
#pragma unroll
        for (int mt = 0; mt < 4; ++mt)
#pragma unroll
            for (int nt = 0; nt < 4; ++nt)
#pragma unroll
                for (int e = 0; e < 4; ++e) {
                    const int m = m0 + wm + mt * 16 + rq * 4 + e;
                    const int n = n0 + wn + nt * 16 + col;
                    const float v = acc[mt][nt][e];
                    const unsigned short h = f2b(v);
                    Yhi[(size_t)m * DIM + n] = h;
                    Ylo[(size_t)m * DIM + n] = f2b(v - b2f(h));
                }
    } else {
        // V: write transposed, Vt[b][n][s], 4 consecutive s per ushort4
#pragma unroll
        for (int mt = 0; mt < 4; ++mt)
#pragma unroll
            for (int nt = 0; nt < 4; ++nt) {
                const int m = m0 + wm + mt * 16 + rq * 4;      // 4-aligned
                const int bb = m >> 11, s = m & (SEQ - 1);
                const int n = n0 + wn + nt * 16 + col;
                ushort4 pk;
                pk.x = f2b(acc[mt][nt][0]);
                pk.y = f2b(acc[mt][nt][1]);
                pk.z = f2b(acc[mt][nt][2]);
                pk.w = f2b(acc[mt][nt][3]);
                *(ushort4*)(Vt + (size_t)bb * DIM * SEQ + (size_t)n * SEQ + s) = pk;
            }
    }
}

// ---------------------------------------------------------------------------
// s_gemm: S[b] = (Y[b] . X[b]^T) * 1/32, masked to -inf via 512 KB bitmask.
// 3-term split bf16; A = Y hi/lo, B = X hi/lo (per batch). fp32 output.
// ---------------------------------------------------------------------------
__global__ __launch_bounds__(256) void s_gemm_kernel(
    const unsigned short* __restrict__ Yhi, const unsigned short* __restrict__ Ylo,
    const unsigned short* __restrict__ Xhi, const unsigned short* __restrict__ Xlo,
    const unsigned int* __restrict__ bm, float* __restrict__ Sc)
{
    __shared__ unsigned short Ah[128 * 32], Al[128 * 32];
    __shared__ unsigned short Bh[128 * 32], Bl[128 * 32];

    const int tid = threadIdx.x;
    const int w = tid >> 6, lane = tid & 63;
    const int wm = (w >> 1) * 64, wn = (w & 1) * 64;
    const int m0 = blockIdx.y * 128, n0 = blockIdx.x * 128;
    const int b = blockIdx.z;

    const unsigned short* __restrict__ Ahg = Yhi + (size_t)b * SEQ * DIM;
    const unsigned short* __restrict__ Alg = Ylo + (size_t)b * SEQ * DIM;
    const unsigned short* __restrict__ Bhg = Xhi + (size_t)b * SEQ * DIM;
    const unsigned short* __restrict__ Blg = Xlo + (size_t)b * SEQ * DIM;
    float* __restrict__ Sb = Sc + (size_t)b * SEQ * SEQ;

    f32x4 acc[4][4];
#pragma unroll
    for (int i = 0; i < 4; ++i)
#pragma unroll
        for (int j = 0; j < 4; ++j) acc[i][j] = (f32x4){0.f, 0.f, 0.f, 0.f};

    const int fr = lane & 15, quad = lane >> 4;
    const int qsw = quad ^ ((fr >> 2) & 3);

    for (int k0 = 0; k0 < DIM; k0 += 32) {
        stage_async(Ahg, DIM, m0, k0, Ah, tid);
        stage_async(Alg, DIM, m0, k0, Al, tid);
        stage_async(Bhg, DIM, n0, k0, Bh, tid);
        stage_async(Blg, DIM, n0, k0, Bl, tid);
        __syncthreads();

        bf16x8 ah[4], al[4];
#pragma unroll
        for (int mt = 0; mt < 4; ++mt) {
            ah[mt] = fragr(Ah, wm + mt * 16 + fr, qsw);
            al[mt] = fragr(Al, wm + mt * 16 + fr, qsw);
        }
#pragma unroll
        for (int nt = 0; nt < 4; ++nt) {
            const bf16x8 bh = fragr(Bh, wn + nt * 16 + fr, qsw);
            const bf16x8 bl = fragr(Bl, wn + nt * 16 + fr, qsw);
#pragma unroll
            for (int mt = 0; mt < 4; ++mt) {
                acc[mt][nt] = __builtin_amdgcn_mfma_f32_16x16x32_bf16(ah[mt], bh, acc[mt][nt], 0, 0, 0);
                acc[mt][nt] = __builtin_amdgcn_mfma_f32_16x16x32_bf16(ah[mt], bl, acc[mt][nt], 0, 0, 0);
                acc[mt][nt] = __builtin_amdgcn_mfma_f32_16x16x32_bf16(al[mt], bh, acc[mt][nt], 0, 0, 0);
            }
        }
        __syncthreads();
    }

    const int col = lane & 15, rq = lane >> 4;
#pragma unroll
    for (int mt = 0; mt < 4; ++mt)
#pragma unroll
        for (int nt = 0; nt < 4; ++nt)
#pragma unroll
            for (int e = 0; e < 4; ++e) {
                const int m = m0 + wm + mt * 16 + rq * 4 + e;
                const int n = n0 + wn + nt * 16 + col;
                const float v = acc[mt][nt][e] * 0.03125f;
                const unsigned int w32 = bm[((size_t)m * SEQ + n) >> 5];
                Sb[(size_t)m * SEQ + n] = ((w32 >> (n & 31)) & 1u) ? -INFINITY : v;
            }
}

// ---------------------------------------------------------------------------
// Row softmax on pre-masked, pre-scaled fp32 S; writes bf16 P in place
// (row r -> first 2048 ushorts of the row's 16 KB).
// ---------------------------------------------------------------------------
__global__ __launch_bounds__(256) void softmax_kernel(float* __restrict__ Sc)
{
    const int r = blockIdx.x;          // b*2048 + m
    float* __restrict__ row = Sc + (size_t)r * SEQ;

    const int tid  = threadIdx.x;
    const int lane = tid & 63;
    const int wid  = tid >> 6;

    float x[8];
    float mx = -INFINITY;
#pragma unroll
    for (int j = 0; j < 8; ++j) {
        x[j] = row[tid + j * 256];
        mx = fmaxf(mx, x[j]);
    }
    __shared__ float redm[4];
#pragma unroll
    for (int off = 32; off > 0; off >>= 1)
        mx = fmaxf(mx, __shfl_down(mx, off, 64));
    if (lane == 0) redm[wid] = mx;
    __syncthreads();
    mx = fmaxf(fmaxf(redm[0], redm[1]), fmaxf(redm[2], redm[3]));

    float sum = 0.f;
#pragma unroll
    for (int j = 0; j < 8; ++j) {
        const float e = __expf(x[j] - mx);
        x[j] = e;
        sum += e;
    }
    __shared__ float reds[4];
#pragma unroll
    for (int off = 32; off > 0; off >>= 1)
        sum += __shfl_down(sum, off, 64);
    if (lane == 0) reds[wid] = sum;
    __syncthreads();
    sum = (reds[0] + reds[1]) + (reds[2] + reds[3]);

    const float inv = 1.0f / sum;
    unsigned short* __restrict__ prow = (unsigned short*)row;
#pragma unroll
    for (int j = 0; j < 8; ++j)
        prow[tid + j * 256] = f2b(x[j] * inv);
}

// ---------------------------------------------------------------------------
// O[b] = P[b] @ V[b]: single bf16 MFMA, BK=64 (two staged sub-tiles/barrier).
// A = P rows (stride 4096 ushorts), B = Vt rows (n-major, k contiguous).
// ---------------------------------------------------------------------------
__global__ __launch_bounds__(256) void pv_mfma_kernel(
    const unsigned short* __restrict__ P, const unsigned short* __restrict__ Vt,
    float* __restrict__ O)
{
    __shared__ unsigned short As[2][128 * 32], Bs[2][128 * 32];

    const int tid = threadIdx.x;
    const int w = tid >> 6, lane = tid & 63;
    const int wm = (w >> 1) * 64, wn = (w & 1) * 64;
    const int m0 = blockIdx.y * 128, n0 = blockIdx.x * 128;
    const int b = blockIdx.z;

    const unsigned short* __restrict__ Ag = P + (size_t)b * SEQ * (2 * SEQ);
    const unsigned short* __restrict__ Bg = Vt + (size_t)b * DIM * SEQ;
    float* __restrict__ Ob = O + (size_t)b * SEQ * DIM;

    f32x4 acc[4][4];
#pragma unroll
    for (int i = 0; i < 4; ++i)
#pragma unroll
        for (int j = 0; j < 4; ++j) acc[i][j] = (f32x4){0.f, 0.f, 0.f, 0.f};

    const int fr = lane & 15, quad = lane >> 4;
    const int qsw = quad ^ ((fr >> 2) & 3);

    for (int k0 = 0; k0 < SEQ; k0 += 64) {
        stage_async(Ag, 2 * SEQ, m0, k0,      As[0], tid);
        stage_async(Ag, 2 * SEQ, m0, k0 + 32, As[1], tid);
        stage_async(Bg, SEQ,     n0, k0,      Bs[0], tid);
        stage_async(Bg, SEQ,     n0, k0 + 32, Bs[1], tid);
        __syncthreads();

#pragma unroll
        for (int s = 0; s < 2; ++s) {
            bf16x8 af[4];
#pragma unroll
            for (int mt = 0; mt < 4; ++mt)
                af[mt] = fragr(As[s], wm + mt * 16 + fr, qsw);
#pragma unroll
            for (int nt = 0; nt < 4; ++nt) {
                const bf16x8 bfg = fragr(Bs[s], wn + nt * 16 + fr, qsw);
#pragma unroll
                for (int mt = 0; mt < 4; ++mt)
                    acc[mt][nt] = __builtin_amdgcn_mfma_f32_16x16x32_bf16(af[mt], bfg, acc[mt][nt], 0, 0, 0);
            }
        }
        __syncthreads();
    }

    const int col = lane & 15, rq = lane >> 4;
#pragma unroll
    for (int mt = 0; mt < 4; ++mt)
#pragma unroll
        for (int nt = 0; nt < 4; ++nt)
#pragma unroll
            for (int e = 0; e < 4; ++e) {
                const int m = m0 + wm + mt * 16 + rq * 4 + e;
                const int n = n0 + wn + nt * 16 + col;
                Ob[(size_t)m * DIM + n] = acc[mt][nt][e];
            }
}

// ---------------------------------------------------------------------------
// Workspace layout (bytes), total used = 155 713 536 (<= 167 772 160):
//   Xhi/Xlo/Yhi/Ylo/Vt : 5 x 16 777 216   (bf16 [8192][1024]-sized each)
//   Mthi/Mtlo          : 2 x  2 097 152   (bf16 [1024][1024])
//   Sc                 : 67 108 864       (fp32 [4][2048][2048])
//   bitmask            :    524 288       (after Sc; persists through s_gemm)
// Transients aliased INSIDE Sc (consumed before s_gemm writes Sc):
//   Whi/Wlo (2x4.2 MB) + WvT (2.1 MB) + Mtp (8x4.2 MB fp32) = 48.2 MB
// P (bf16) written in place into Sc rows (row r at ushort offset r*4096).
// ---------------------------------------------------------------------------
extern "C" void kernel_launch(void* const* d_in, const int* in_sizes, int n_in,
                              void* d_out, int out_size, void* d_ws, size_t ws_size,
                              hipStream_t stream)
{
    const float* x    = (const float*)d_in[0];
    const int*   mask = (const int*)d_in[1];
    const float* wq   = (const float*)d_in[2];
    const float* wk   = (const float*)d_in[3];
    const float* wv   = (const float*)d_in[4];
    float* out = (float*)d_out;

    const size_t NQ = (size_t)BATCH * SEQ * DIM;     // 8 388 608
    const size_t NM = (size_t)DIM * DIM;             // 1 048 576
    unsigned short* Xhi  = (unsigned short*)d_ws;
    unsigned short* Xlo  = Xhi + NQ;
    unsigned short* Yhi  = Xlo + NQ;
    unsigned short* Ylo  = Yhi + NQ;
    unsigned short* Vt   = Ylo + NQ;
    unsigned short* Mthi = Vt + NQ;
    unsigned short* Mtlo = Mthi + NM;
    float* Sc = (float*)(Mtlo + NM);
    unsigned long long* bm = (unsigned long long*)(Sc + (size_t)BATCH * SEQ * SEQ);

    unsigned short* Whi = (unsigned short*)Sc;       // transient aliases in Sc
    unsigned short* Wlo = Whi + 2 * NM;
    unsigned short* WvT = Wlo + 2 * NM;
    float* Mtp = (float*)(WvT + NM);                 // 8 x NM fp32

    // 1. One dispatch: X hi/lo, Wq/Wk hi/lo, WvT, mask -> bitmask
    convert_all_kernel<<<dim3(2176), 256, 0, stream>>>(
        x, wq, wk, wv, mask, Xhi, Xlo, Whi, Wlo, WvT, bm);
    // 2. Mt = Wk.Wq^T (K-split x8, fp32 partials), then reduce + hi/lo split
    m_gemm_kernel<<<dim3(8, 8, 8), 256, 0, stream>>>(Whi, Wlo, Mtp);
    m_reduce_kernel<<<dim3(NM / 4 / 256), 256, 0, stream>>>(Mtp, Mthi, Mtlo);
    // 3. z=0: Y = X.Mt^T (hi/lo out); z=1: V = X.WvT^T written as Vt[b][d][s]
    yv_gemm_kernel<<<dim3(DIM / 128, (BATCH * SEQ) / 128, 2), 256, 0, stream>>>(
        Xhi, Xlo, Mthi, Mtlo, WvT, Yhi, Ylo, Vt);
    // 4. S = masked, scaled Y.X^T per batch (fp32 scores, bitmask)
    s_gemm_kernel<<<dim3(SEQ / 128, SEQ / 128, BATCH), 256, 0, stream>>>(
        Yhi, Ylo, Xhi, Xlo, (const unsigned int*)bm, Sc);
    // 5. softmax; writes bf16 P in place
    softmax_kernel<<<dim3(BATCH * SEQ), 256, 0, stream>>>(Sc);
    // 6. O = P @ V
    pv_mfma_kernel<<<dim3(DIM / 128, SEQ / 128, BATCH), 256, 0, stream>>>(
        (const unsigned short*)Sc, Vt, out);
}